// Round 2
// baseline (192.996 us; speedup 1.0000x reference)
//
#include <hip/hip_runtime.h>

#define BATCH     32768
#define IN_DIM    256
#define N_NEURONS 128
#define DEG1      8                    // MAX_DEGREE+1
#define FEAT      (IN_DIM * DEG1)      // 2048
#define XR4       (IN_DIM / 4)         // 64 float4 per x row
#define NBLK      256                  // 1 block/CU
#define NTHR      1024                 // 16 waves/block
#define RPW       8                    // rows per wave: 256*16*8 = 32768

// ---------------------------------------------------------------------------
// out[b] = sum_f X[b,f]*csum[f] with csum[f] = sum_n coeffs[n,f].
//
// Round 6 theory: the 78 µs is NOT our kernels (kan_fwd is ~7 µs BW-bound —
// proven by round 5's occupancy 4x being neutral). The timed region contains
// the harness's 256 MiB d_ws re-poison fill (43.5 µs, visible in rocprof) plus
// ~10 µs/dispatch launch gaps. So: fuse to ONE kernel and use ZERO workspace.
// Each block redundantly computes csum (1 MiB coeffs, L2-resident; 256 MiB
// aggregate ≈ 8 µs) into LDS in the EXACT same fp order as the old
// reduce_coeffs (group-of-4 sequential, then the same pairwise tree over 32
// groups) -> bit-identical results. The 8 x-row loads per wave are issued
// before the csum phase so HBM latency hides under it.
//
// NOTE (prior session): cooperative-kernel grid.sync() costs ~100 µs at this
// grid size on gfx950 — do not revisit.
// ---------------------------------------------------------------------------

__global__ __launch_bounds__(NTHR) void kan_fused(const float* __restrict__ x,
                                                  const float* __restrict__ coeffs,
                                                  float* __restrict__ out) {
    __shared__ float csum[FEAT];                       // 8 KiB
    const int t    = threadIdx.x;
    const int lane = t & 63;
    const int wave = t >> 6;                           // 0..15
    const int row0 = (blockIdx.x * (NTHR / 64) + wave) * RPW;

    // ---- issue x loads first: latency hides under the csum phase ----------
    float4 xv[RPW];
    const float4* xr = (const float4*)x + (size_t)row0 * XR4 + lane;
#pragma unroll
    for (int r = 0; r < RPW; ++r) xv[r] = xr[(size_t)r * XR4];

    // ---- per-block csum, bit-identical order to old reduce_coeffs ---------
    // column c: gs[g] = coeffs[4g,c]+coeffs[4g+1,c]+coeffs[4g+2,c]+coeffs[4g+3,c]
    // (sequential), then pairwise tree gs[g] += gs[g+stride], stride 16..1.
#pragma unroll
    for (int half = 0; half < 2; ++half) {
        const int col = t + half * NTHR;               // 0..2047, coalesced
        float gs[32];
#pragma unroll
        for (int g = 0; g < 32; ++g) {
            const float* p = coeffs + (size_t)(g * 4) * FEAT + col;
            float s = p[0];
            s += p[(size_t)1 * FEAT];
            s += p[(size_t)2 * FEAT];
            s += p[(size_t)3 * FEAT];
            gs[g] = s;
        }
#pragma unroll
        for (int stride = 16; stride >= 1; stride >>= 1) {
#pragma unroll
            for (int g = 0; g < 16; ++g) {
                if (g < stride) gs[g] += gs[g + stride];   // unrolled: static
            }
        }
        csum[col] = gs[0];
    }
    __syncthreads();

    // ---- per-lane coefficients from LDS (lane l owns dims 4l..4l+3) -------
    float c[4][8];
    const float4* c4 = (const float4*)csum + (size_t)lane * 8;
#pragma unroll
    for (int j = 0; j < 4; ++j) {
        float4 a = c4[j * 2];
        float4 b = c4[j * 2 + 1];
        c[j][0] = a.x; c[j][1] = a.y; c[j][2] = a.z; c[j][3] = a.w;
        c[j][4] = b.x; c[j][5] = b.y; c[j][6] = b.z; c[j][7] = b.w;
    }

    // ---- Chebyshev eval, identical recurrence/order to previous kernel ----
    float acc[RPW];
#pragma unroll
    for (int r = 0; r < RPW; ++r) {
        float xs[4] = {xv[r].x, xv[r].y, xv[r].z, xv[r].w};
        float a = 0.f;
#pragma unroll
        for (int j = 0; j < 4; ++j) {
            const float xx = xs[j];
            const float two_x = xx + xx;
            a = fmaf(c[j][1], xx, a + c[j][0]);   // T0=1, T1=x
            float tp = 1.f, tc = xx;
#pragma unroll
            for (int d = 2; d < 8; ++d) {
                float tn = fmaf(two_x, tc, -tp);  // T_d = 2x*T_{d-1} - T_{d-2}
                a = fmaf(c[j][d], tn, a);
                tp = tc; tc = tn;
            }
        }
        acc[r] = a;
    }

    // ---- same shfl_down tree and store mapping as before ------------------
#pragma unroll
    for (int rq = 0; rq < RPW / 4; ++rq) {
        float s[4];
#pragma unroll
        for (int k = 0; k < 4; ++k) {
            float a = acc[rq * 4 + k];
#pragma unroll
            for (int off = 32; off > 0; off >>= 1) a += __shfl_down(a, off, 64);
            s[k] = a;
        }
        if (lane == 0)
            ((float4*)out)[row0 / 4 + rq] = make_float4(s[0], s[1], s[2], s[3]);
    }
}

extern "C" void kernel_launch(void* const* d_in, const int* in_sizes, int n_in,
                              void* d_out, int out_size, void* d_ws, size_t ws_size,
                              hipStream_t stream) {
    const float* x      = (const float*)d_in[0];   // [32768, 256]
    const float* coeffs = (const float*)d_in[1];   // [128, 2048]
    float* out = (float*)d_out;                    // [32768, 1]
    (void)d_ws; (void)ws_size;                     // deliberately unused

    kan_fused<<<NBLK, NTHR, 0, stream>>>(x, coeffs, out);
}

// Round 3
// 130.629 us; speedup vs baseline: 1.4774x; 1.4774x over previous
//
#include <hip/hip_runtime.h>

#define BATCH     32768
#define IN_DIM    256
#define N_NEURONS 128
#define DEG1      8                    // MAX_DEGREE+1
#define FEAT      (IN_DIM * DEG1)      // 2048
#define RS        (FEAT / 4)           // 512 float4 per coeff row
#define XR4       (IN_DIM / 4)         // 64 float4 per x row
#define NBLK      256                  // 1 block/CU
#define NTHR      512                  // 8 waves/block
#define RPW       16                   // rows per wave: 256*8*16 = 32768

// ---------------------------------------------------------------------------
// out[b] = sum_f X[b,f]*csum[f] with csum[f] = sum_n coeffs[n,f].
//
// Round 7: single-dispatch fused kernel (round 6 proved the 256 MiB ws poison
// fill ~43.5 µs is UNCONDITIONAL, so the only lever is kernel time + gap
// count; two-kernel pays 2 extra ~7 µs gaps). Round 6's version spilled
// (VGPR_Count=64 via launch_bounds(1024), 146 MB scratch writes, 143 µs).
// Fixes: (a) 512-thread blocks + __launch_bounds__(512,2) -> 256-VGPR cap,
// ~150 live regs fit with zero scratch; (b) csum tree re-scheduled to 16 live
// partials (g and g+16 combined immediately — same pairwise adds, identical
// bits); (c) float4 csum loads (4x fewer instructions, 1 KiB/wave/req).
// x rows prefetched into registers before csum so the 32 MiB HBM read hides
// under the L2-resident coeff pass. All fp orders match the verified round-0
// kernel -> absmax stays 0.0625.
//
// NOTE: cooperative grid.sync() ~100 µs on gfx950 — do not revisit.
// ---------------------------------------------------------------------------

__global__ __launch_bounds__(NTHR, 2) void kan_fused(const float* __restrict__ x,
                                                     const float* __restrict__ coeffs,
                                                     float* __restrict__ out) {
    __shared__ float csum[FEAT];                       // 8 KiB
    const int t    = threadIdx.x;
    const int lane = t & 63;
    const int wave = t >> 6;                           // 0..7
    const int row0 = (blockIdx.x * (NTHR / 64) + wave) * RPW;

    // ---- prefetch all x rows; held in regs through the csum phase ---------
    float4 xv[RPW];
    const float4* xr = (const float4*)x + (size_t)row0 * XR4 + lane;
#pragma unroll
    for (int r = 0; r < RPW; ++r) xv[r] = xr[(size_t)r * XR4];

    // ---- per-block csum, bit-identical values to the old reduce_coeffs ----
    // thread owns float4-column t (scalar cols 4t..4t+3).
    // gs[g] = ((c[4g]+c[4g+1])+c[4g+2])+c[4g+3]; tree strides 16,8,4,2,1.
    // Scheduled as s1[g] = gs[g]+gs[g+16] (the stride-16 step) immediately,
    // so only 16 float4 partials are live — same adds, same results.
    const float4* cp = (const float4*)coeffs + t;
    float4 s1[16];
#pragma unroll
    for (int g = 0; g < 16; ++g) {
        const float4* pa = cp + (size_t)(4 * g) * RS;
        const float4* pb = cp + (size_t)(4 * (g + 16)) * RS;
        float4 a0 = pa[0], a1 = pa[RS], a2 = pa[2 * RS], a3 = pa[3 * RS];
        float4 b0 = pb[0], b1 = pb[RS], b2 = pb[2 * RS], b3 = pb[3 * RS];
        float4 s;
        s.x = (((a0.x + a1.x) + a2.x) + a3.x) + (((b0.x + b1.x) + b2.x) + b3.x);
        s.y = (((a0.y + a1.y) + a2.y) + a3.y) + (((b0.y + b1.y) + b2.y) + b3.y);
        s.z = (((a0.z + a1.z) + a2.z) + a3.z) + (((b0.z + b1.z) + b2.z) + b3.z);
        s.w = (((a0.w + a1.w) + a2.w) + a3.w) + (((b0.w + b1.w) + b2.w) + b3.w);
        s1[g] = s;
    }
#pragma unroll
    for (int stride = 8; stride >= 1; stride >>= 1) {
#pragma unroll
        for (int g = 0; g < 8; ++g) {
            if (g < stride) {
                s1[g].x += s1[g + stride].x;
                s1[g].y += s1[g + stride].y;
                s1[g].z += s1[g + stride].z;
                s1[g].w += s1[g + stride].w;
            }
        }
    }
    ((float4*)csum)[t] = s1[0];
    __syncthreads();

    // ---- per-lane coefficients from LDS (lane l owns dims 4l..4l+3) -------
    float c[4][8];
    const float4* c4 = (const float4*)csum + (size_t)lane * 8;
#pragma unroll
    for (int j = 0; j < 4; ++j) {
        float4 a = c4[j * 2];
        float4 b = c4[j * 2 + 1];
        c[j][0] = a.x; c[j][1] = a.y; c[j][2] = a.z; c[j][3] = a.w;
        c[j][4] = b.x; c[j][5] = b.y; c[j][6] = b.z; c[j][7] = b.w;
    }

    // ---- Chebyshev eval, identical recurrence/order to round-0 kernel -----
    float acc[RPW];
#pragma unroll
    for (int r = 0; r < RPW; ++r) {
        float xs[4] = {xv[r].x, xv[r].y, xv[r].z, xv[r].w};
        float a = 0.f;
#pragma unroll
        for (int j = 0; j < 4; ++j) {
            const float xx = xs[j];
            const float two_x = xx + xx;
            a = fmaf(c[j][1], xx, a + c[j][0]);   // T0=1, T1=x
            float tp = 1.f, tc = xx;
#pragma unroll
            for (int d = 2; d < 8; ++d) {
                float tn = fmaf(two_x, tc, -tp);  // T_d = 2x*T_{d-1} - T_{d-2}
                a = fmaf(c[j][d], tn, a);
                tp = tc; tc = tn;
            }
        }
        acc[r] = a;
    }

    // ---- same shfl_down tree and store mapping as round 0 -----------------
#pragma unroll
    for (int rq = 0; rq < RPW / 4; ++rq) {
        float s[4];
#pragma unroll
        for (int k = 0; k < 4; ++k) {
            float a = acc[rq * 4 + k];
#pragma unroll
            for (int off = 32; off > 0; off >>= 1) a += __shfl_down(a, off, 64);
            s[k] = a;
        }
        if (lane == 0)
            ((float4*)out)[row0 / 4 + rq] = make_float4(s[0], s[1], s[2], s[3]);
    }
}

extern "C" void kernel_launch(void* const* d_in, const int* in_sizes, int n_in,
                              void* d_out, int out_size, void* d_ws, size_t ws_size,
                              hipStream_t stream) {
    const float* x      = (const float*)d_in[0];   // [32768, 256]
    const float* coeffs = (const float*)d_in[1];   // [128, 2048]
    float* out = (float*)d_out;                    // [32768, 1]
    (void)d_ws; (void)ws_size;                     // deliberately unused

    kan_fused<<<NBLK, NTHR, 0, stream>>>(x, coeffs, out);
}

// Round 4
// 94.855 us; speedup vs baseline: 2.0346x; 1.3771x over previous
//
#include <hip/hip_runtime.h>

#define BATCH     32768
#define IN_DIM    256
#define N_NEURONS 128
#define DEG1      8                    // MAX_DEGREE+1
#define FEAT      (IN_DIM * DEG1)      // 2048
#define RS        (FEAT / 4)           // 512 float4 per coeff row
#define XR4       (IN_DIM / 4)         // 64 float4 per x row
#define NBLK      256                  // 1 block per 2 CUs offered twice -> 2 blocks/CU
#define NTHR      512                  // 8 waves/block
#define RPW       16                   // rows per wave: 256*8*16 = 32768
#define XB        4                    // x-row prefetch batch (rolling)

// ---------------------------------------------------------------------------
// out[b] = sum_f X[b,f]*csum[f] with csum[f] = sum_n coeffs[n,f].
//
// Round 8: fused single-dispatch (the 256 MiB ws poison fill ~43.5 µs is
// unconditional; two-kernel pays 2 extra ~8 µs launch gaps). Round 7 still
// spilled: (512,2) caps VGPR at 128 (4 waves/SIMD), but xv[16]+s1[16] = 128+
// regs live -> 87.8 MB scratch writes, 70 µs. Fix: rolling 4-row x batch
// (double-buffered, 32 regs) and per-batch reduce+store (4 accs live).
// Peak live ~95 regs -> fits 128, zero scratch.
// Work floor: 256 MB L2 coeff reads ≈7.4 µs + 32 MB HBM x ≈5.5 µs.
//
// All fp orders identical to the verified round-0/7 kernels (group-of-4 sums,
// g/g+16 pair, tree 8..1, Chebyshev recurrence, shfl tree, store map) ->
// absmax stays 0.0625.
//
// NOTE: cooperative grid.sync() ~100 µs on gfx950 — do not revisit.
// ---------------------------------------------------------------------------

__global__ __launch_bounds__(NTHR, 2) void kan_fused(const float* __restrict__ x,
                                                     const float* __restrict__ coeffs,
                                                     float* __restrict__ out) {
    __shared__ float csum[FEAT];                       // 8 KiB
    const int t    = threadIdx.x;
    const int lane = t & 63;
    const int wave = t >> 6;                           // 0..7
    const int row0 = (blockIdx.x * (NTHR / 64) + wave) * RPW;

    const float4* xr = (const float4*)x + (size_t)row0 * XR4 + lane;

    // ---- prefetch x batch 0 (rows 0..3): hides under the csum phase -------
    float4 xa[XB], xb[XB];
#pragma unroll
    for (int r = 0; r < XB; ++r) xa[r] = xr[(size_t)r * XR4];

    // ---- per-block csum, bit-identical values to old reduce_coeffs --------
    // thread owns float4-column t. gs[g]=((c4g+c4g+1)+c4g+2)+c4g+3;
    // s1[g]=gs[g]+gs[g+16] (the stride-16 tree step), then strides 8..1.
    const float4* cp = (const float4*)coeffs + t;
    float4 s1[16];
#pragma unroll
    for (int g = 0; g < 16; ++g) {
        const float4* pa = cp + (size_t)(4 * g) * RS;
        const float4* pb = cp + (size_t)(4 * (g + 16)) * RS;
        float4 a0 = pa[0], a1 = pa[RS], a2 = pa[2 * RS], a3 = pa[3 * RS];
        float4 b0 = pb[0], b1 = pb[RS], b2 = pb[2 * RS], b3 = pb[3 * RS];
        float4 s;
        s.x = (((a0.x + a1.x) + a2.x) + a3.x) + (((b0.x + b1.x) + b2.x) + b3.x);
        s.y = (((a0.y + a1.y) + a2.y) + a3.y) + (((b0.y + b1.y) + b2.y) + b3.y);
        s.z = (((a0.z + a1.z) + a2.z) + a3.z) + (((b0.z + b1.z) + b2.z) + b3.z);
        s.w = (((a0.w + a1.w) + a2.w) + a3.w) + (((b0.w + b1.w) + b2.w) + b3.w);
        s1[g] = s;
    }
#pragma unroll
    for (int stride = 8; stride >= 1; stride >>= 1) {
#pragma unroll
        for (int g = 0; g < 8; ++g) {
            if (g < stride) {
                s1[g].x += s1[g + stride].x;
                s1[g].y += s1[g + stride].y;
                s1[g].z += s1[g + stride].z;
                s1[g].w += s1[g + stride].w;
            }
        }
    }
    ((float4*)csum)[t] = s1[0];
    __syncthreads();

    // ---- per-lane coefficients from LDS (lane l owns dims 4l..4l+3) -------
    float c[4][8];
    const float4* c4 = (const float4*)csum + (size_t)lane * 8;
#pragma unroll
    for (int j = 0; j < 4; ++j) {
        float4 a = c4[j * 2];
        float4 b = c4[j * 2 + 1];
        c[j][0] = a.x; c[j][1] = a.y; c[j][2] = a.z; c[j][3] = a.w;
        c[j][4] = b.x; c[j][5] = b.y; c[j][6] = b.z; c[j][7] = b.w;
    }

    // ---- 4 batches of 4 rows: prefetch next batch, compute, reduce, store -
#pragma unroll
    for (int b = 0; b < RPW / XB; ++b) {
        if (b < RPW / XB - 1) {
#pragma unroll
            for (int r = 0; r < XB; ++r)
                xb[r] = xr[(size_t)((b + 1) * XB + r) * XR4];
        }
        float s[XB];
#pragma unroll
        for (int k = 0; k < XB; ++k) {
            float xs[4] = {xa[k].x, xa[k].y, xa[k].z, xa[k].w};
            float a = 0.f;
#pragma unroll
            for (int j = 0; j < 4; ++j) {
                const float xx = xs[j];
                const float two_x = xx + xx;
                a = fmaf(c[j][1], xx, a + c[j][0]);   // T0=1, T1=x
                float tp = 1.f, tc = xx;
#pragma unroll
                for (int d = 2; d < 8; ++d) {
                    float tn = fmaf(two_x, tc, -tp);  // T_d = 2x*T_{d-1} - T_{d-2}
                    a = fmaf(c[j][d], tn, a);
                    tp = tc; tc = tn;
                }
            }
            // same shfl_down tree as round 0
#pragma unroll
            for (int off = 32; off > 0; off >>= 1) a += __shfl_down(a, off, 64);
            s[k] = a;
        }
        if (lane == 0)
            ((float4*)out)[row0 / 4 + b] = make_float4(s[0], s[1], s[2], s[3]);
#pragma unroll
        for (int r = 0; r < XB; ++r) xa[r] = xb[r];
    }
}

extern "C" void kernel_launch(void* const* d_in, const int* in_sizes, int n_in,
                              void* d_out, int out_size, void* d_ws, size_t ws_size,
                              hipStream_t stream) {
    const float* x      = (const float*)d_in[0];   // [32768, 256]
    const float* coeffs = (const float*)d_in[1];   // [128, 2048]
    float* out = (float*)d_out;                    // [32768, 1]
    (void)d_ws; (void)ws_size;                     // deliberately unused

    kan_fused<<<NBLK, NTHR, 0, stream>>>(x, coeffs, out);
}

// Round 5
// 83.026 us; speedup vs baseline: 2.3245x; 1.1425x over previous
//
#include <hip/hip_runtime.h>

#define BATCH     32768
#define IN_DIM    256
#define N_NEURONS 128
#define DEG1      8                    // MAX_DEGREE+1
#define FEAT      (IN_DIM * DEG1)      // 2048
#define RS        (FEAT / 4)           // 512 float4 per coeff row
#define XR4       (IN_DIM / 4)         // 64 float4 per x row
#define NBLK      256                  // 1 block/CU
#define NTHR      1024                 // 16 waves/block -> 4 waves/SIMD
#define WPB       (NTHR / 64)          // 16
#define RPW       8                    // rows per wave: 256*16*8 = 32768
#define XB        4                    // x-row prefetch batch (rolling)

// ---------------------------------------------------------------------------
// out[b] = sum_f X[b,f]*csum[f] with csum[f] = sum_n coeffs[n,f].
//
// Round 9: R4 (44 µs kernel) was latency-bound: 2 waves/SIMD (Occupancy 20%,
// VALUBusy 7.5%) with a 128-deep serial csum load chain per thread. csum
// redundancy is per-BLOCK, TLP is per-WAVE -> 1024-thread blocks double
// waves/CU (16) at ZERO extra coeff traffic, and the csum tree is split
// even-g/odd-g across the two half-blocks so each thread's chain halves to
// 64 loads. Split is BIT-EXACT: tree pairs (g,g+8),(+4),(+2) stay within a
// parity class; only the final w0+w1 crosses, via an LDS bridge, in the
// original order. R2's 1024-thr spill avoided via __launch_bounds__(1024,4)
// (4 waves/EU -> 128-VGPR cap; peak live ~95). csum LDS padded (+1 float4
// per 8) to cut the per-lane coeff-read bank conflict 32-way -> 8-way.
//
// Pre-committed: if kernel stays >=35 µs, fused csum is request-rate-bound
// -> revert to two-kernel structure next round.
// NOTE: cooperative grid.sync() ~100 µs on gfx950 — do not revisit.
// ---------------------------------------------------------------------------

__global__ __launch_bounds__(NTHR, 4) void kan_fused(const float* __restrict__ x,
                                                     const float* __restrict__ coeffs,
                                                     float* __restrict__ out) {
    // physical float4 index = c + (c>>3): 512 -> 576 slots (9216 B)
    __shared__ float4 csum4[576];
    __shared__ float4 bridge[512];                     // 8 KiB, odd-half w[1]
    const int t    = threadIdx.x;
    const int lane = t & 63;
    const int wave = t >> 6;                           // 0..15
    const int row0 = (blockIdx.x * WPB + wave) * RPW;

    // ---- prefetch x batch 0: hides under the csum phase -------------------
    float4 xa[XB], xb[XB];
    const float4* xr = (const float4*)x + (size_t)row0 * XR4 + lane;
#pragma unroll
    for (int r = 0; r < XB; ++r) xa[r] = xr[(size_t)r * XR4];

    // ---- per-block csum, bit-identical to the verified reduce_coeffs ------
    // gs[g]=((c4g+c4g+1)+c4g+2)+c4g+3; s1[g]=gs[g]+gs[g+16]; tree 8,4,2,1.
    // Threads 0-511 own even g (s1[0,2,..,14]) for col t; threads 512-1023
    // own odd g for col t-512. (g,g+8) pairs preserve parity -> each half
    // reduces independently to w[parity]; final csum = w[0]+w[1] via LDS.
    {
        const int col = t & 511;
        const int odd = t >> 9;                        // wave-uniform
        const float4* cp = (const float4*)coeffs + col;
        float4 s1[8];
#pragma unroll
        for (int i = 0; i < 8; ++i) {
            const int g = 2 * i + odd;
            const float4* pa = cp + (size_t)(4 * g) * RS;
            const float4* pb = cp + (size_t)(4 * (g + 16)) * RS;
            float4 a0 = pa[0], a1 = pa[RS], a2 = pa[2 * RS], a3 = pa[3 * RS];
            float4 b0 = pb[0], b1 = pb[RS], b2 = pb[2 * RS], b3 = pb[3 * RS];
            s1[i].x = (((a0.x + a1.x) + a2.x) + a3.x) + (((b0.x + b1.x) + b2.x) + b3.x);
            s1[i].y = (((a0.y + a1.y) + a2.y) + a3.y) + (((b0.y + b1.y) + b2.y) + b3.y);
            s1[i].z = (((a0.z + a1.z) + a2.z) + a3.z) + (((b0.z + b1.z) + b2.z) + b3.z);
            s1[i].w = (((a0.w + a1.w) + a2.w) + a3.w) + (((b0.w + b1.w) + b2.w) + b3.w);
        }
        // u-level: uu[i] = s1-orig[g] + s1-orig[g+8]  (g = 2i+odd)
#pragma unroll
        for (int i = 0; i < 4; ++i) {
            s1[i].x += s1[i + 4].x; s1[i].y += s1[i + 4].y;
            s1[i].z += s1[i + 4].z; s1[i].w += s1[i + 4].w;
        }
        // v-level: v = uu[0]+uu[2], uu[1]+uu[3]   (== u[g]+u[g+4])
        s1[0].x += s1[2].x; s1[0].y += s1[2].y; s1[0].z += s1[2].z; s1[0].w += s1[2].w;
        s1[1].x += s1[3].x; s1[1].y += s1[3].y; s1[1].z += s1[3].z; s1[1].w += s1[3].w;
        // w-level: w[parity] = v_first + v_second
        s1[0].x += s1[1].x; s1[0].y += s1[1].y; s1[0].z += s1[1].z; s1[0].w += s1[1].w;

        if (odd) bridge[col] = s1[0];
        __syncthreads();
        if (!odd) {
            float4 wb = bridge[col];
            float4 r;
            r.x = s1[0].x + wb.x; r.y = s1[0].y + wb.y;
            r.z = s1[0].z + wb.z; r.w = s1[0].w + wb.w;
            csum4[col + (col >> 3)] = r;               // padded layout
        }
        __syncthreads();
    }

    // ---- per-lane coefficients from LDS (lane l owns dims 4l..4l+3) -------
    // logical col4 = lane*8 + j*2 (+1) -> physical = lane*9 + j*2 (+1)
    float c[4][8];
#pragma unroll
    for (int j = 0; j < 4; ++j) {
        float4 a = csum4[lane * 9 + j * 2];
        float4 b = csum4[lane * 9 + j * 2 + 1];
        c[j][0] = a.x; c[j][1] = a.y; c[j][2] = a.z; c[j][3] = a.w;
        c[j][4] = b.x; c[j][5] = b.y; c[j][6] = b.z; c[j][7] = b.w;
    }

    // ---- 2 batches of 4 rows: prefetch, compute, reduce, store ------------
#pragma unroll
    for (int b = 0; b < RPW / XB; ++b) {
        if (b < RPW / XB - 1) {
#pragma unroll
            for (int r = 0; r < XB; ++r)
                xb[r] = xr[(size_t)((b + 1) * XB + r) * XR4];
        }
        float s[XB];
#pragma unroll
        for (int k = 0; k < XB; ++k) {
            float xs[4] = {xa[k].x, xa[k].y, xa[k].z, xa[k].w};
            float a = 0.f;
#pragma unroll
            for (int j = 0; j < 4; ++j) {
                const float xx = xs[j];
                const float two_x = xx + xx;
                a = fmaf(c[j][1], xx, a + c[j][0]);   // T0=1, T1=x
                float tp = 1.f, tc = xx;
#pragma unroll
                for (int d = 2; d < 8; ++d) {
                    float tn = fmaf(two_x, tc, -tp);  // T_d = 2x*T_{d-1} - T_{d-2}
                    a = fmaf(c[j][d], tn, a);
                    tp = tc; tc = tn;
                }
            }
            // same shfl_down tree as round 0
#pragma unroll
            for (int off = 32; off > 0; off >>= 1) a += __shfl_down(a, off, 64);
            s[k] = a;
        }
        if (lane == 0)
            ((float4*)out)[row0 / 4 + b] = make_float4(s[0], s[1], s[2], s[3]);
#pragma unroll
        for (int r = 0; r < XB; ++r) xa[r] = xb[r];
    }
}

extern "C" void kernel_launch(void* const* d_in, const int* in_sizes, int n_in,
                              void* d_out, int out_size, void* d_ws, size_t ws_size,
                              hipStream_t stream) {
    const float* x      = (const float*)d_in[0];   // [32768, 256]
    const float* coeffs = (const float*)d_in[1];   // [128, 2048]
    float* out = (float*)d_out;                    // [32768, 1]
    (void)d_ws; (void)ws_size;                     // deliberately unused

    kan_fused<<<NBLK, NTHR, 0, stream>>>(x, coeffs, out);
}

// Round 6
// 76.689 us; speedup vs baseline: 2.5166x; 1.0826x over previous
//
#include <hip/hip_runtime.h>

#define BATCH     32768
#define IN_DIM    256
#define N_NEURONS 128
#define DEG1      8                    // MAX_DEGREE+1
#define FEAT      (IN_DIM * DEG1)      // 2048
#define F4        (FEAT / 4)           // 512 float4 columns
#define XR4       (IN_DIM / 4)         // 64 float4 per x row
#define RPW       8                    // rows per wave
#define XB        4                    // x-row prefetch batch (rolling)

// ---------------------------------------------------------------------------
// out[b] = sum_f X[b,f]*csum[f] with csum[f] = sum_n coeffs[n,f].
//
// Round 10: REVERT to two-dispatch (round-4 pre-commitment fired). The fused
// single-dispatch carries an inherent 256 MiB aggregate L2 read (>=256 blocks
// x 1 MiB redundant coeff read each) -> measured ~32 µs kernel, total 83 —
// worse than the two-kernel 77.7. Two-dispatch: k1 reads coeffs ONCE (~3 µs),
// k2 is x-BW-bound (32 MiB, floor ~5.3-8 µs). New in k2 vs R0/R1: rolling
// XB=4 double-buffered x prefetch + 16 waves/CU (1024 blk x 256 thr, RPW=8,
// launch_bounds(256,4) -> 128-VGPR cap, live ~75, no spill).
// This run also pins the inter-dispatch overhead: total - fill - (k1+k2).
//
// NOTE: cooperative grid.sync() ~100 µs on gfx950 — do not revisit.
// NOTE: 256 MiB ws poison fill (~43.5 µs) is unconditional (proven round 6).
// ---------------------------------------------------------------------------

// Kernel 1: csum[f] = sum_n coeffs[n, f]. 64 blocks x 256 threads; thread
// (g,c) sums 4 neurons of float4-column c; LDS tree over the 32 groups.
// VERBATIM from the verified round-0 kernel (bit-exact).
__global__ __launch_bounds__(256) void reduce_coeffs(const float* __restrict__ coeffs,
                                                     float* __restrict__ csum) {
    __shared__ float4 part[256];
    const int t = threadIdx.x;
    const int c = t & 7;                     // float4-col within block
    const int g = t >> 3;                    // neuron group of 4
    const int col4 = blockIdx.x * 8 + c;     // 64 * 8 = 512 float4 columns

    const float4* p = (const float4*)coeffs + (size_t)(g * 4) * F4 + col4;
    float4 s = make_float4(0.f, 0.f, 0.f, 0.f);
#pragma unroll
    for (int n = 0; n < 4; ++n) {
        float4 v = p[(size_t)n * F4];
        s.x += v.x; s.y += v.y; s.z += v.z; s.w += v.w;
    }
    part[t] = s;
    __syncthreads();
#pragma unroll
    for (int stride = 128; stride >= 8; stride >>= 1) {
        if (t < stride) {
            float4 o = part[t + stride];
            float4 m = part[t];
            m.x += o.x; m.y += o.y; m.z += o.z; m.w += o.w;
            part[t] = m;
        }
        __syncthreads();
    }
    if (t < 8) ((float4*)csum)[blockIdx.x * 8 + t] = part[t];
}

// Kernel 2: one wave per RPW=8 rows; lane l owns dims 4l..4l+3. x batch 0
// issued FIRST (long pole), csum->regs completes under its latency, then a
// rolling 4-row pipeline: prefetch batch b+1 while computing batch b.
// 1024 blocks x 4 waves: 4096 waves, 16 waves/CU offered.
__global__ __launch_bounds__(256, 4) void kan_fwd(const float* __restrict__ x,
                                                  const float* __restrict__ csum,
                                                  float* __restrict__ out) {
    const int lane = threadIdx.x & 63;
    const int wave = threadIdx.x >> 6;                   // 0..3
    const int row0 = (blockIdx.x * 4 + wave) * RPW;      // 1024 blocks

    // issue x batch 0 before anything else
    float4 xa[XB], xb[XB];
    const float4* xr = (const float4*)x + (size_t)row0 * XR4 + lane;
#pragma unroll
    for (int r = 0; r < XB; ++r) xa[r] = xr[(size_t)r * XR4];

    // per-lane coefficients (lane l owns dims 4l..4l+3): 8 float4 loads,
    // L2-hot broadcast, completes under the x-batch HBM latency.
    float c[4][8];
    const float4* c4 = (const float4*)csum + (size_t)lane * 8;
#pragma unroll
    for (int j = 0; j < 4; ++j) {
        float4 a = c4[j * 2];
        float4 b = c4[j * 2 + 1];
        c[j][0] = a.x; c[j][1] = a.y; c[j][2] = a.z; c[j][3] = a.w;
        c[j][4] = b.x; c[j][5] = b.y; c[j][6] = b.z; c[j][7] = b.w;
    }

    // rolling pipeline: 2 batches of 4 rows
#pragma unroll
    for (int b = 0; b < RPW / XB; ++b) {
        if (b < RPW / XB - 1) {
#pragma unroll
            for (int r = 0; r < XB; ++r)
                xb[r] = xr[(size_t)((b + 1) * XB + r) * XR4];
        }
        float s[XB];
#pragma unroll
        for (int k = 0; k < XB; ++k) {
            float xs[4] = {xa[k].x, xa[k].y, xa[k].z, xa[k].w};
            float a = 0.f;
#pragma unroll
            for (int j = 0; j < 4; ++j) {
                const float xx = xs[j];
                const float two_x = xx + xx;
                a = fmaf(c[j][1], xx, a + c[j][0]);   // T0=1, T1=x
                float tp = 1.f, tc = xx;
#pragma unroll
                for (int d = 2; d < 8; ++d) {
                    float tn = fmaf(two_x, tc, -tp);  // T_d = 2x*T_{d-1} - T_{d-2}
                    a = fmaf(c[j][d], tn, a);
                    tp = tc; tc = tn;
                }
            }
            // same shfl_down tree as round 0 (bit-identical)
#pragma unroll
            for (int off = 32; off > 0; off >>= 1) a += __shfl_down(a, off, 64);
            s[k] = a;
        }
        if (lane == 0)
            ((float4*)out)[row0 / 4 + b] = make_float4(s[0], s[1], s[2], s[3]);
#pragma unroll
        for (int r = 0; r < XB; ++r) xa[r] = xb[r];
    }
}

extern "C" void kernel_launch(void* const* d_in, const int* in_sizes, int n_in,
                              void* d_out, int out_size, void* d_ws, size_t ws_size,
                              hipStream_t stream) {
    const float* x      = (const float*)d_in[0];   // [32768, 256]
    const float* coeffs = (const float*)d_in[1];   // [128, 2048]
    float* out  = (float*)d_out;                   // [32768, 1]
    float* csum = (float*)d_ws;                    // 2048 floats scratch

    reduce_coeffs<<<64, 256, 0, stream>>>(coeffs, csum);
    kan_fwd<<<BATCH / (4 * RPW), 256, 0, stream>>>(x, csum, out);
}